// Round 1
// baseline (726.800 us; speedup 1.0000x reference)
//
#include <hip/hip_runtime.h>

// Attention_37074157699274 : fused qkv-proj + 8-head attention (n=32,d=64) + out-proj
// x[4,1024,32,256] f32, W_qkv[256,1536] f32, W_out[512,256] f32, b_out[256] f32
// out[4,1024,32,256] f32. bf16 MFMA compute, fp32 softmax/accum.

#define NHEADS 8

typedef __bf16 bf16x8 __attribute__((ext_vector_type(8)));
typedef __bf16 bf16x4 __attribute__((ext_vector_type(4)));
typedef float f32x4 __attribute__((ext_vector_type(4)));

__device__ __forceinline__ f32x4 mfma16(bf16x8 a, bf16x8 b, f32x4 c) {
  return __builtin_amdgcn_mfma_f32_16x16x32_bf16(a, b, c, 0, 0, 0);
}

// ws layout: [0,786432) WqkvT bf16 [1536][256] ; [786432,1048576) WoutT bf16 [256][512]
__global__ __launch_bounds__(256) void prep_weights(const float* __restrict__ Wqkv,
                                                    const float* __restrict__ Wout,
                                                    __bf16* __restrict__ WqkvT,
                                                    __bf16* __restrict__ WoutT) {
  int idx = blockIdx.x * 256 + threadIdx.x;
  if (idx < 1536 * 256) {
    int n = idx >> 8, k = idx & 255;
    WqkvT[idx] = (__bf16)Wqkv[k * 1536 + n];
  }
  if (idx < 256 * 512) {
    int n = idx >> 9, k = idx & 511;
    WoutT[idx] = (__bf16)Wout[k * 256 + n];
  }
}

__global__ __launch_bounds__(256) void attn_fused(const float* __restrict__ x,
                                                  const __bf16* __restrict__ WqkvT,
                                                  const __bf16* __restrict__ WoutT,
                                                  const float* __restrict__ b_out,
                                                  float* __restrict__ out) {
  // strides padded to kill/soften bank conflicts, all 16B-aligned rows
  __shared__ __align__(16) __bf16 Xs[32 * 264];  // x tile bf16 [32][256] stride 264
  __shared__ __align__(16) __bf16 qs[32 * 72];   // q [32][64] (reused for O)
  __shared__ __align__(16) __bf16 ks[32 * 72];   // k [32][64]
  __shared__ __align__(16) __bf16 vT[64 * 40];   // v transposed [64][32]
  __shared__ __align__(16) float  Ss[32 * 36];   // scores fp32
  __shared__ __align__(16) __bf16 Ps[32 * 40];   // softmax probs bf16

  const int tid  = threadIdx.x;
  const int wave = tid >> 6;
  const int lane = tid & 63;
  const int quad = lane >> 4;
  const int l16  = lane & 15;
  const int bp   = blockIdx.x;  // 0..4095 == (b,p)

  // ---- stage X tile -> LDS bf16 ----
  const float4* xg = (const float4*)(x + (size_t)bp * 32 * 256);
  for (int i = tid; i < 32 * 64; i += 256) {
    int row = i >> 6, c4 = i & 63;
    float4 v = xg[i];
    bf16x4 pk;
    pk[0] = (__bf16)v.x; pk[1] = (__bf16)v.y; pk[2] = (__bf16)v.z; pk[3] = (__bf16)v.w;
    *(bf16x4*)(&Xs[row * 264 + c4 * 4]) = pk;
  }
  __syncthreads();

  const f32x4 zero = {0.f, 0.f, 0.f, 0.f};
  f32x4 outacc[8];  // wave's out tiles: ntile = wave + g*4, both mtiles
#pragma unroll
  for (int i = 0; i < 8; i++) outacc[i] = zero;

  for (int h = 0; h < NHEADS; h++) {
    // ---- q,k,v = X @ Wqkv slices : 12 (mat,ntile) combos over 4 waves ----
    for (int c = wave; c < 12; c += 4) {
      int mat = c >> 2;  // 0=q 1=k 2=v
      int nt  = c & 3;
      const __bf16* bptr = WqkvT + (size_t)(mat * 512 + h * 64 + nt * 16 + l16) * 256 + quad * 8;
      f32x4 a0 = zero, a1 = zero;
#pragma unroll
      for (int kk = 0; kk < 8; kk++) {
        bf16x8 bf = *(const bf16x8*)(bptr + kk * 32);
        bf16x8 x0 = *(const bf16x8*)(&Xs[l16 * 264 + kk * 32 + quad * 8]);
        bf16x8 x1 = *(const bf16x8*)(&Xs[(16 + l16) * 264 + kk * 32 + quad * 8]);
        a0 = mfma16(x0, bf, a0);
        a1 = mfma16(x1, bf, a1);
      }
      if (mat < 2) {
        __bf16* dst = (mat == 0) ? qs : ks;
#pragma unroll
        for (int r = 0; r < 4; r++) {
          dst[(quad * 4 + r) * 72 + nt * 16 + l16]        = (__bf16)a0[r];
          dst[(16 + quad * 4 + r) * 72 + nt * 16 + l16]   = (__bf16)a1[r];
        }
      } else {
        // v stored transposed: vT[d][token]; C/D layout makes this 4 contiguous bf16
        bf16x4 p0, p1;
#pragma unroll
        for (int r = 0; r < 4; r++) { p0[r] = (__bf16)a0[r]; p1[r] = (__bf16)a1[r]; }
        *(bf16x4*)(&vT[(nt * 16 + l16) * 40 + quad * 4])      = p0;
        *(bf16x4*)(&vT[(nt * 16 + l16) * 40 + 16 + quad * 4]) = p1;
      }
    }
    __syncthreads();

    // ---- S = q @ k^T * scale : 4 16x16 tiles, one per wave ----
    {
      int mt = wave >> 1, nt = wave & 1;
      f32x4 acc = zero;
#pragma unroll
      for (int kk = 0; kk < 2; kk++) {
        bf16x8 a = *(const bf16x8*)(&qs[(mt * 16 + l16) * 72 + kk * 32 + quad * 8]);
        bf16x8 b = *(const bf16x8*)(&ks[(nt * 16 + l16) * 72 + kk * 32 + quad * 8]);
        acc = mfma16(a, b, acc);
      }
#pragma unroll
      for (int r = 0; r < 4; r++)
        Ss[(mt * 16 + quad * 4 + r) * 36 + nt * 16 + l16] = acc[r] * 0.125f;  // 64^-0.5
    }
    __syncthreads();

    // ---- softmax rows (fp32) ----
    if (tid < 32) {
      float rowv[32];
      float m = -1e30f;
#pragma unroll
      for (int j = 0; j < 32; j++) { rowv[j] = Ss[tid * 36 + j]; m = fmaxf(m, rowv[j]); }
      float s = 0.f;
#pragma unroll
      for (int j = 0; j < 32; j++) { rowv[j] = __expf(rowv[j] - m); s += rowv[j]; }
      float inv = 1.f / s;
#pragma unroll
      for (int j = 0; j < 32; j++) Ps[tid * 40 + j] = (__bf16)(rowv[j] * inv);
    }
    __syncthreads();

    // ---- O = P @ v : wave handles d-tile nt=wave, both mtiles; K=32 one mfma ----
    {
      int nt = wave;
      bf16x8 b  = *(const bf16x8*)(&vT[(nt * 16 + l16) * 40 + quad * 8]);
      bf16x8 a0 = *(const bf16x8*)(&Ps[l16 * 40 + quad * 8]);
      bf16x8 a1 = *(const bf16x8*)(&Ps[(16 + l16) * 40 + quad * 8]);
      f32x4 o0 = mfma16(a0, b, zero);
      f32x4 o1 = mfma16(a1, b, zero);
#pragma unroll
      for (int r = 0; r < 4; r++) {  // O -> LDS (reuse qs)
        qs[(quad * 4 + r) * 72 + nt * 16 + l16]      = (__bf16)o0[r];
        qs[(16 + quad * 4 + r) * 72 + nt * 16 + l16] = (__bf16)o1[r];
      }
    }
    __syncthreads();

    // ---- out += O @ W_out[h*64:(h+1)*64, :] ----
#pragma unroll
    for (int g = 0; g < 4; g++) {
      int ntile = wave + g * 4;
#pragma unroll
      for (int kk = 0; kk < 2; kk++) {
        bf16x8 b  = *(const bf16x8*)(WoutT + (size_t)(ntile * 16 + l16) * 512 + h * 64 + kk * 32 + quad * 8);
        bf16x8 a0 = *(const bf16x8*)(&qs[l16 * 72 + kk * 32 + quad * 8]);
        bf16x8 a1 = *(const bf16x8*)(&qs[(16 + l16) * 72 + kk * 32 + quad * 8]);
        outacc[g * 2 + 0] = mfma16(a0, b, outacc[g * 2 + 0]);
        outacc[g * 2 + 1] = mfma16(a1, b, outacc[g * 2 + 1]);
      }
    }
    __syncthreads();  // before next head overwrites qs/ks/vT
  }

  // ---- epilogue: add bias, store fp32 ----
  float* og = out + (size_t)bp * 32 * 256;
#pragma unroll
  for (int g = 0; g < 4; g++) {
    int ntile = wave + g * 4;
    float bias = b_out[ntile * 16 + l16];
#pragma unroll
    for (int mt = 0; mt < 2; mt++) {
      f32x4 a = outacc[g * 2 + mt];
#pragma unroll
      for (int r = 0; r < 4; r++)
        og[(mt * 16 + quad * 4 + r) * 256 + ntile * 16 + l16] = a[r] + bias;
    }
  }
}

extern "C" void kernel_launch(void* const* d_in, const int* in_sizes, int n_in,
                              void* d_out, int out_size, void* d_ws, size_t ws_size,
                              hipStream_t stream) {
  const float* x     = (const float*)d_in[0];
  const float* Wqkv  = (const float*)d_in[1];
  const float* Wout  = (const float*)d_in[2];
  const float* bout  = (const float*)d_in[3];
  float* out = (float*)d_out;

  __bf16* WqkvT = (__bf16*)d_ws;
  __bf16* WoutT = (__bf16*)((char*)d_ws + (size_t)1536 * 256 * 2);

  prep_weights<<<1536, 256, 0, stream>>>(Wqkv, Wout, WqkvT, WoutT);
  attn_fused<<<4096, 256, 0, stream>>>(x, WqkvT, WoutT, bout, out);
}

// Round 2
// 665.865 us; speedup vs baseline: 1.0915x; 1.0915x over previous
//
#include <hip/hip_runtime.h>

// Attention_37074157699274 : fused qkv-proj + 8-head attention (n=32,d=64) + out-proj
// Round 2: heads wave-parallel, in-register softmax, 3 barriers/block (was 41).

#define NHEADS 8

typedef __bf16 bf16x8 __attribute__((ext_vector_type(8)));
typedef __bf16 bf16x4 __attribute__((ext_vector_type(4)));
typedef float f32x4 __attribute__((ext_vector_type(4)));

__device__ __forceinline__ f32x4 mfma16(bf16x8 a, bf16x8 b, f32x4 c) {
  return __builtin_amdgcn_mfma_f32_16x16x32_bf16(a, b, c, 0, 0, 0);
}

// ws: [0,786432) WqkvT bf16 [1536][256] ; [786432,1048576) WoutT bf16 [256][512]
__global__ __launch_bounds__(256) void prep_weights(const float* __restrict__ Wqkv,
                                                    const float* __restrict__ Wout,
                                                    __bf16* __restrict__ WqkvT,
                                                    __bf16* __restrict__ WoutT) {
  int idx = blockIdx.x * 256 + threadIdx.x;
  if (idx < 1536 * 256) {
    int n = idx >> 8, k = idx & 255;
    WqkvT[idx] = (__bf16)Wqkv[k * 1536 + n];
  }
  if (idx < 256 * 512) {
    int n = idx >> 9, k = idx & 511;
    WoutT[idx] = (__bf16)Wout[k * 256 + n];
  }
}

__global__ __launch_bounds__(256, 2) void attn_fused(const float* __restrict__ x,
                                                     const __bf16* __restrict__ WqkvT,
                                                     const __bf16* __restrict__ WoutT,
                                                     const float* __restrict__ b_out,
                                                     float* __restrict__ out) {
  __shared__ __align__(16) __bf16 Xs[32 * 264];    // x tile bf16, stride 264
  __shared__ __align__(16) __bf16 pool[4 * 7168];  // per-wave q/k/vT; later Os[32][520]

  const int tid  = threadIdx.x;
  const int wave = tid >> 6;
  const int lane = tid & 63;
  const int quad = lane >> 4;
  const int l16  = lane & 15;
  const int bp   = blockIdx.x;

  __bf16* qs = pool + wave * 7168;  // [32][72]  (reused as P scratch)
  __bf16* ks = qs + 2304;           // [32][72]
  __bf16* vT = ks + 2304;           // [64][40]  v transposed
  __bf16* Os = pool;                // [32][520] after barrier (overlays pool)

  // ---- stage X tile -> LDS bf16 ----
  const float4* xg = (const float4*)(x + (size_t)bp * 32 * 256);
  for (int i = tid; i < 32 * 64; i += 256) {
    int row = i >> 6, c4 = i & 63;
    float4 v = xg[i];
    bf16x4 pk;
    pk[0] = (__bf16)v.x; pk[1] = (__bf16)v.y; pk[2] = (__bf16)v.z; pk[3] = (__bf16)v.w;
    *(bf16x4*)(&Xs[row * 264 + c4 * 4]) = pk;
  }
  __syncthreads();  // barrier 1

  // ---- hoist X A-fragments into registers (reused across all qkv mfmas) ----
  bf16x8 xa0[8], xa1[8];
#pragma unroll
  for (int kk = 0; kk < 8; kk++) {
    xa0[kk] = *(const bf16x8*)(&Xs[l16 * 264 + kk * 32 + quad * 8]);
    xa1[kk] = *(const bf16x8*)(&Xs[(16 + l16) * 264 + kk * 32 + quad * 8]);
  }

  const f32x4 zero = {0.f, 0.f, 0.f, 0.f};
  bf16x4 obf[2][2][4];  // O output [hh][mt][nt], bf16, kept in regs until Os write

#pragma unroll
  for (int hh = 0; hh < 2; hh++) {
    const int h = wave * 2 + hh;  // this wave's head — everything below is wave-private

    // ---- q,k,v = X @ Wqkv[:, h slices] ----
#pragma unroll
    for (int mat = 0; mat < 3; mat++) {
#pragma unroll
      for (int nt = 0; nt < 4; nt++) {
        const __bf16* bptr = WqkvT + (size_t)(mat * 512 + h * 64 + nt * 16 + l16) * 256 + quad * 8;
        f32x4 a0 = zero, a1 = zero;
#pragma unroll
        for (int kk = 0; kk < 8; kk++) {
          bf16x8 bf = *(const bf16x8*)(bptr + kk * 32);
          a0 = mfma16(xa0[kk], bf, a0);
          a1 = mfma16(xa1[kk], bf, a1);
        }
        if (mat == 0) {  // q — fold softmax scale 1/8 here
#pragma unroll
          for (int r = 0; r < 4; r++) {
            qs[(quad * 4 + r) * 72 + nt * 16 + l16]      = (__bf16)(a0[r] * 0.125f);
            qs[(16 + quad * 4 + r) * 72 + nt * 16 + l16] = (__bf16)(a1[r] * 0.125f);
          }
        } else if (mat == 1) {
#pragma unroll
          for (int r = 0; r < 4; r++) {
            ks[(quad * 4 + r) * 72 + nt * 16 + l16]      = (__bf16)a0[r];
            ks[(16 + quad * 4 + r) * 72 + nt * 16 + l16] = (__bf16)a1[r];
          }
        } else {  // v transposed: vT[d][token]
          bf16x4 p0, p1;
#pragma unroll
          for (int r = 0; r < 4; r++) { p0[r] = (__bf16)a0[r]; p1[r] = (__bf16)a1[r]; }
          *(bf16x4*)(&vT[(nt * 16 + l16) * 40 + quad * 4])      = p0;
          *(bf16x4*)(&vT[(nt * 16 + l16) * 40 + 16 + quad * 4]) = p1;
        }
      }
    }

    // ---- S = q @ k^T (scale folded into q) : all 4 tiles in this wave ----
    f32x4 s[2][2] = {{zero, zero}, {zero, zero}};
#pragma unroll
    for (int kk = 0; kk < 2; kk++) {
      bf16x8 a0 = *(const bf16x8*)(&qs[l16 * 72 + kk * 32 + quad * 8]);
      bf16x8 a1 = *(const bf16x8*)(&qs[(16 + l16) * 72 + kk * 32 + quad * 8]);
      bf16x8 b0 = *(const bf16x8*)(&ks[l16 * 72 + kk * 32 + quad * 8]);
      bf16x8 b1 = *(const bf16x8*)(&ks[(16 + l16) * 72 + kk * 32 + quad * 8]);
      s[0][0] = mfma16(a0, b0, s[0][0]);
      s[0][1] = mfma16(a0, b1, s[0][1]);
      s[1][0] = mfma16(a1, b0, s[1][0]);
      s[1][1] = mfma16(a1, b1, s[1][1]);
    }

    // ---- in-register softmax. Row i=mt*16+quad*4+r lives in lanes quad*16+{0..15}. ----
    float mx[2][4], sm[2][4], e[2][2][4];
#pragma unroll
    for (int mt = 0; mt < 2; mt++)
#pragma unroll
      for (int r = 0; r < 4; r++) mx[mt][r] = fmaxf(s[mt][0][r], s[mt][1][r]);
#pragma unroll
    for (int mask = 1; mask < 16; mask <<= 1)
#pragma unroll
      for (int mt = 0; mt < 2; mt++)
#pragma unroll
        for (int r = 0; r < 4; r++) mx[mt][r] = fmaxf(mx[mt][r], __shfl_xor(mx[mt][r], mask));
#pragma unroll
    for (int mt = 0; mt < 2; mt++)
#pragma unroll
      for (int r = 0; r < 4; r++) {
        e[mt][0][r] = __expf(s[mt][0][r] - mx[mt][r]);
        e[mt][1][r] = __expf(s[mt][1][r] - mx[mt][r]);
        sm[mt][r] = e[mt][0][r] + e[mt][1][r];
      }
#pragma unroll
    for (int mask = 1; mask < 16; mask <<= 1)
#pragma unroll
      for (int mt = 0; mt < 2; mt++)
#pragma unroll
        for (int r = 0; r < 4; r++) sm[mt][r] += __shfl_xor(sm[mt][r], mask);

    // ---- P -> LDS (C-layout, reuse qs) -> reread in A-layout (wave-private) ----
#pragma unroll
    for (int mt = 0; mt < 2; mt++) {
      float inv0 = 1.f / sm[mt][0], inv1 = 1.f / sm[mt][1], inv2 = 1.f / sm[mt][2], inv3 = 1.f / sm[mt][3];
#pragma unroll
      for (int nt = 0; nt < 2; nt++) {
        qs[(mt * 16 + quad * 4 + 0) * 72 + nt * 16 + l16] = (__bf16)(e[mt][nt][0] * inv0);
        qs[(mt * 16 + quad * 4 + 1) * 72 + nt * 16 + l16] = (__bf16)(e[mt][nt][1] * inv1);
        qs[(mt * 16 + quad * 4 + 2) * 72 + nt * 16 + l16] = (__bf16)(e[mt][nt][2] * inv2);
        qs[(mt * 16 + quad * 4 + 3) * 72 + nt * 16 + l16] = (__bf16)(e[mt][nt][3] * inv3);
      }
    }
    bf16x8 pa0 = *(const bf16x8*)(&qs[l16 * 72 + quad * 8]);
    bf16x8 pa1 = *(const bf16x8*)(&qs[(16 + l16) * 72 + quad * 8]);

    // ---- O = P @ v ----
#pragma unroll
    for (int nt = 0; nt < 4; nt++) {
      bf16x8 b = *(const bf16x8*)(&vT[(nt * 16 + l16) * 40 + quad * 8]);
      f32x4 o0 = mfma16(pa0, b, zero);
      f32x4 o1 = mfma16(pa1, b, zero);
#pragma unroll
      for (int r = 0; r < 4; r++) {
        obf[hh][0][nt][r] = (__bf16)o0[r];
        obf[hh][1][nt][r] = (__bf16)o1[r];
      }
    }
  }

  __syncthreads();  // barrier 2: all waves done with private pool regions

  // ---- write O (all heads) into Os[32][520] overlaying pool ----
#pragma unroll
  for (int hh = 0; hh < 2; hh++) {
    int h = wave * 2 + hh;
#pragma unroll
    for (int mt = 0; mt < 2; mt++)
#pragma unroll
      for (int nt = 0; nt < 4; nt++)
#pragma unroll
        for (int r = 0; r < 4; r++)
          Os[(mt * 16 + quad * 4 + r) * 520 + h * 64 + nt * 16 + l16] = obf[hh][mt][nt][r];
  }
  __syncthreads();  // barrier 3

  // ---- out = O @ W_out + b : wave owns ntiles {wave, wave+4, wave+8, wave+12} ----
  f32x4 outacc[4][2];
#pragma unroll
  for (int g = 0; g < 4; g++) { outacc[g][0] = zero; outacc[g][1] = zero; }
#pragma unroll
  for (int g = 0; g < 4; g++) {
    int ntile = wave + g * 4;
    const __bf16* bbase = WoutT + (size_t)(ntile * 16 + l16) * 512 + quad * 8;
#pragma unroll
    for (int kk = 0; kk < 16; kk++) {
      bf16x8 b  = *(const bf16x8*)(bbase + kk * 32);
      bf16x8 a0 = *(const bf16x8*)(&Os[l16 * 520 + kk * 32 + quad * 8]);
      bf16x8 a1 = *(const bf16x8*)(&Os[(16 + l16) * 520 + kk * 32 + quad * 8]);
      outacc[g][0] = mfma16(a0, b, outacc[g][0]);
      outacc[g][1] = mfma16(a1, b, outacc[g][1]);
    }
  }

  // ---- epilogue: bias + store ----
  float* og = out + (size_t)bp * 32 * 256;
#pragma unroll
  for (int g = 0; g < 4; g++) {
    int ntile = wave + g * 4;
    float bias = b_out[ntile * 16 + l16];
#pragma unroll
    for (int mt = 0; mt < 2; mt++) {
      f32x4 a = outacc[g][mt];
#pragma unroll
      for (int r = 0; r < 4; r++)
        og[(mt * 16 + quad * 4 + r) * 256 + ntile * 16 + l16] = a[r] + bias;
    }
  }
}

extern "C" void kernel_launch(void* const* d_in, const int* in_sizes, int n_in,
                              void* d_out, int out_size, void* d_ws, size_t ws_size,
                              hipStream_t stream) {
  const float* x    = (const float*)d_in[0];
  const float* Wqkv = (const float*)d_in[1];
  const float* Wout = (const float*)d_in[2];
  const float* bout = (const float*)d_in[3];
  float* out = (float*)d_out;

  __bf16* WqkvT = (__bf16*)d_ws;
  __bf16* WoutT = (__bf16*)((char*)d_ws + (size_t)1536 * 256 * 2);

  prep_weights<<<1536, 256, 0, stream>>>(Wqkv, Wout, WqkvT, WoutT);
  attn_fused<<<4096, 256, 0, stream>>>(x, WqkvT, WoutT, bout, out);
}

// Round 3
// 404.775 us; speedup vs baseline: 1.7956x; 1.6450x over previous
//
#include <hip/hip_runtime.h>

// Attention_37074157699274 : fused qkv-proj + 8-head attention (n=32,d=64) + out-proj
// R3: fragment-packed weights (coalesced 1KiB wave loads), distance-2 double-buffered
// weight prefetch, non-temporal x/out streaming to protect L2 weight residency.

typedef __bf16 bf16x8 __attribute__((ext_vector_type(8)));
typedef __bf16 bf16x4 __attribute__((ext_vector_type(4)));
typedef float f32x4 __attribute__((ext_vector_type(4)));
typedef float f32x4v __attribute__((ext_vector_type(4)));

__device__ __forceinline__ f32x4 mfma16(bf16x8 a, bf16x8 b, f32x4 c) {
  return __builtin_amdgcn_mfma_f32_16x16x32_bf16(a, b, c, 0, 0, 0);
}

// ws: [0,786432) WqkvP bf16 packed frags ; [786432,1048576) WoutP bf16 packed frags
// WqkvP: frag t = (combo*8 + kk)*64 + lane, combo = (mat*8+h)*4+nt, 8 ele each:
//   ele j = Wqkv[k][n], n = mat*512+h*64+nt*16+(lane&15), k = kk*32+(lane>>4)*8+j
// WoutP: frag t = (ntile*16 + kk)*64 + lane:
//   ele j = Wout[k][n], n = ntile*16+(lane&15), k = kk*32+(lane>>4)*8+j
__global__ __launch_bounds__(256) void prep_weights(const float* __restrict__ Wqkv,
                                                    const float* __restrict__ Wout,
                                                    __bf16* __restrict__ WqkvP,
                                                    __bf16* __restrict__ WoutP) {
  int t = blockIdx.x * 256 + threadIdx.x;
  if (t < 49152) {
    int lane = t & 63, rest = t >> 6;
    int kk = rest & 7, combo = rest >> 3;
    int nt = combo & 3, mh = combo >> 2;
    int h = mh & 7, mat = mh >> 3;
    int l16 = lane & 15, quad = lane >> 4;
    int n = mat * 512 + h * 64 + nt * 16 + l16;
    int k0 = kk * 32 + quad * 8;
    __bf16* dst = WqkvP + (size_t)t * 8;
#pragma unroll
    for (int j = 0; j < 8; j++) dst[j] = (__bf16)Wqkv[(size_t)(k0 + j) * 1536 + n];
  }
  int t2 = t - 49152;
  if (t2 >= 0 && t2 < 16384) {
    int lane = t2 & 63, rest = t2 >> 6;
    int kk = rest & 15, ntile = rest >> 4;
    int l16 = lane & 15, quad = lane >> 4;
    int n = ntile * 16 + l16;
    int k0 = kk * 32 + quad * 8;
    __bf16* dst = WoutP + (size_t)t2 * 8;
#pragma unroll
    for (int j = 0; j < 8; j++) dst[j] = (__bf16)Wout[(size_t)(k0 + j) * 256 + n];
  }
}

__global__ __launch_bounds__(256, 2) void attn_fused(const float* __restrict__ x,
                                                     const __bf16* __restrict__ WqkvP,
                                                     const __bf16* __restrict__ WoutP,
                                                     const float* __restrict__ b_out,
                                                     float* __restrict__ out) {
  __shared__ __align__(16) __bf16 Xs[32 * 264];    // x tile bf16, stride 264
  __shared__ __align__(16) __bf16 pool[4 * 7168];  // per-wave q/k/vT; later Os[32][520]

  const int tid  = threadIdx.x;
  const int wave = tid >> 6;
  const int lane = tid & 63;
  const int quad = lane >> 4;
  const int l16  = lane & 15;
  const int bp   = blockIdx.x;

  __bf16* qs = pool + wave * 7168;  // [32][72]  (reused as P scratch)
  __bf16* ks = qs + 2304;           // [32][72]
  __bf16* vT = ks + 2304;           // [64][40]  v transposed
  __bf16* Os = pool;                // [32][520] after barrier 2 (overlays pool)

  // ---- stage X tile -> LDS bf16 (non-temporal: don't thrash L2 weights) ----
  const f32x4v* xg = (const f32x4v*)(x + (size_t)bp * 32 * 256);
  for (int i = tid; i < 32 * 64; i += 256) {
    int row = i >> 6, c4 = i & 63;
    f32x4v v = __builtin_nontemporal_load(xg + i);
    bf16x4 pk;
    pk[0] = (__bf16)v[0]; pk[1] = (__bf16)v[1]; pk[2] = (__bf16)v[2]; pk[3] = (__bf16)v[3];
    *(bf16x4*)(&Xs[row * 264 + c4 * 4]) = pk;
  }
  __syncthreads();  // barrier 1

  // ---- weight-fragment load helpers (each: 8 perfectly-coalesced 1KiB wave loads) ----
  bf16x8 bb[2][8];
  auto load_qkv = [&](int c, bf16x8* dst) {
    int hloc = wave * 2 + (c >= 12 ? 1 : 0);
    int r = (c >= 12) ? c - 12 : c;
    int mat = r >> 2, nt = r & 3;
    const __bf16* base = WqkvP + ((size_t)((mat * 8 + hloc) * 4 + nt)) * 4096 + lane * 8;
#pragma unroll
    for (int kk = 0; kk < 8; kk++) dst[kk] = *(const bf16x8*)(base + kk * 512);
  };

  load_qkv(0, bb[0]);
  load_qkv(1, bb[1]);

  // ---- hoist X A-fragments (reused by all 24 qkv combos) ----
  bf16x8 xa0[8], xa1[8];
#pragma unroll
  for (int kk = 0; kk < 8; kk++) {
    xa0[kk] = *(const bf16x8*)(&Xs[l16 * 264 + kk * 32 + quad * 8]);
    xa1[kk] = *(const bf16x8*)(&Xs[(16 + l16) * 264 + kk * 32 + quad * 8]);
  }

  const f32x4 zero = {0.f, 0.f, 0.f, 0.f};
  bf16x4 obf[2][2][4];  // O output [hh][mt][nt] in regs until Os write

#pragma unroll
  for (int hh = 0; hh < 2; hh++) {
#pragma unroll
    for (int r = 0; r < 12; r++) {
      const int c = hh * 12 + r;
      const int mat = r >> 2, nt = r & 3;
      f32x4 a0 = zero, a1 = zero;
#pragma unroll
      for (int kk = 0; kk < 8; kk++) {
        a0 = mfma16(xa0[kk], bb[c & 1][kk], a0);
        a1 = mfma16(xa1[kk], bb[c & 1][kk], a1);
      }
      if (c + 2 < 24) load_qkv(c + 2, bb[c & 1]);  // distance-2 prefetch (after last use)
      if (mat == 0) {  // q — fold softmax scale 1/8
#pragma unroll
        for (int rr = 0; rr < 4; rr++) {
          qs[(quad * 4 + rr) * 72 + nt * 16 + l16]      = (__bf16)(a0[rr] * 0.125f);
          qs[(16 + quad * 4 + rr) * 72 + nt * 16 + l16] = (__bf16)(a1[rr] * 0.125f);
        }
      } else if (mat == 1) {
#pragma unroll
        for (int rr = 0; rr < 4; rr++) {
          ks[(quad * 4 + rr) * 72 + nt * 16 + l16]      = (__bf16)a0[rr];
          ks[(16 + quad * 4 + rr) * 72 + nt * 16 + l16] = (__bf16)a1[rr];
        }
      } else {  // v transposed: vT[d][token]
        bf16x4 p0, p1;
#pragma unroll
        for (int rr = 0; rr < 4; rr++) { p0[rr] = (__bf16)a0[rr]; p1[rr] = (__bf16)a1[rr]; }
        *(bf16x4*)(&vT[(nt * 16 + l16) * 40 + quad * 4])      = p0;
        *(bf16x4*)(&vT[(nt * 16 + l16) * 40 + 16 + quad * 4]) = p1;
      }
    }

    // ---- S = q @ k^T (scale folded into q), wave-private ----
    f32x4 s[2][2] = {{zero, zero}, {zero, zero}};
#pragma unroll
    for (int kk = 0; kk < 2; kk++) {
      bf16x8 a0 = *(const bf16x8*)(&qs[l16 * 72 + kk * 32 + quad * 8]);
      bf16x8 a1 = *(const bf16x8*)(&qs[(16 + l16) * 72 + kk * 32 + quad * 8]);
      bf16x8 b0 = *(const bf16x8*)(&ks[l16 * 72 + kk * 32 + quad * 8]);
      bf16x8 b1 = *(const bf16x8*)(&ks[(16 + l16) * 72 + kk * 32 + quad * 8]);
      s[0][0] = mfma16(a0, b0, s[0][0]);
      s[0][1] = mfma16(a0, b1, s[0][1]);
      s[1][0] = mfma16(a1, b0, s[1][0]);
      s[1][1] = mfma16(a1, b1, s[1][1]);
    }

    // ---- in-register softmax: row i lives in the 16 lanes of one quad ----
    float mx[2][4], sm[2][4], e[2][2][4];
#pragma unroll
    for (int mt = 0; mt < 2; mt++)
#pragma unroll
      for (int rr = 0; rr < 4; rr++) mx[mt][rr] = fmaxf(s[mt][0][rr], s[mt][1][rr]);
#pragma unroll
    for (int mask = 1; mask < 16; mask <<= 1)
#pragma unroll
      for (int mt = 0; mt < 2; mt++)
#pragma unroll
        for (int rr = 0; rr < 4; rr++) mx[mt][rr] = fmaxf(mx[mt][rr], __shfl_xor(mx[mt][rr], mask));
#pragma unroll
    for (int mt = 0; mt < 2; mt++)
#pragma unroll
      for (int rr = 0; rr < 4; rr++) {
        e[mt][0][rr] = __expf(s[mt][0][rr] - mx[mt][rr]);
        e[mt][1][rr] = __expf(s[mt][1][rr] - mx[mt][rr]);
        sm[mt][rr] = e[mt][0][rr] + e[mt][1][rr];
      }
#pragma unroll
    for (int mask = 1; mask < 16; mask <<= 1)
#pragma unroll
      for (int mt = 0; mt < 2; mt++)
#pragma unroll
        for (int rr = 0; rr < 4; rr++) sm[mt][rr] += __shfl_xor(sm[mt][rr], mask);

    // ---- P -> LDS (C-layout, reuse qs) -> reread in A-layout ----
#pragma unroll
    for (int mt = 0; mt < 2; mt++) {
      float inv0 = 1.f / sm[mt][0], inv1 = 1.f / sm[mt][1], inv2 = 1.f / sm[mt][2], inv3 = 1.f / sm[mt][3];
#pragma unroll
      for (int nt = 0; nt < 2; nt++) {
        qs[(mt * 16 + quad * 4 + 0) * 72 + nt * 16 + l16] = (__bf16)(e[mt][nt][0] * inv0);
        qs[(mt * 16 + quad * 4 + 1) * 72 + nt * 16 + l16] = (__bf16)(e[mt][nt][1] * inv1);
        qs[(mt * 16 + quad * 4 + 2) * 72 + nt * 16 + l16] = (__bf16)(e[mt][nt][2] * inv2);
        qs[(mt * 16 + quad * 4 + 3) * 72 + nt * 16 + l16] = (__bf16)(e[mt][nt][3] * inv3);
      }
    }
    bf16x8 pa0 = *(const bf16x8*)(&qs[l16 * 72 + quad * 8]);
    bf16x8 pa1 = *(const bf16x8*)(&qs[(16 + l16) * 72 + quad * 8]);

    // ---- O = P @ v ----
#pragma unroll
    for (int nt = 0; nt < 4; nt++) {
      bf16x8 b = *(const bf16x8*)(&vT[(nt * 16 + l16) * 40 + quad * 8]);
      f32x4 o0 = mfma16(pa0, b, zero);
      f32x4 o1 = mfma16(pa1, b, zero);
#pragma unroll
      for (int rr = 0; rr < 4; rr++) {
        obf[hh][0][nt][rr] = (__bf16)o0[rr];
        obf[hh][1][nt][rr] = (__bf16)o1[rr];
      }
    }
  }

  // ---- prefetch first two out-proj weight batches before the barriers ----
  bf16x8 wb[2][8];
  auto load_wout = [&](int b, bf16x8* dst) {
    int g = b >> 1, ntile = wave + g * 4, kk0 = (b & 1) * 8;
    const __bf16* base = WoutP + ((size_t)(ntile * 16 + kk0) * 64 + lane) * 8;
#pragma unroll
    for (int j = 0; j < 8; j++) dst[j] = *(const bf16x8*)(base + j * 512);
  };
  load_wout(0, wb[0]);
  load_wout(1, wb[1]);

  __syncthreads();  // barrier 2: waves done with private pool regions

  // ---- write O (all heads) into Os[32][520] overlaying pool ----
#pragma unroll
  for (int hh = 0; hh < 2; hh++) {
    int h = wave * 2 + hh;
#pragma unroll
    for (int mt = 0; mt < 2; mt++)
#pragma unroll
      for (int nt = 0; nt < 4; nt++)
#pragma unroll
        for (int rr = 0; rr < 4; rr++)
          Os[(mt * 16 + quad * 4 + rr) * 520 + h * 64 + nt * 16 + l16] = obf[hh][mt][nt][rr];
  }
  __syncthreads();  // barrier 3

  // ---- out = O @ W_out + b : 8 pipelined weight batches ----
  f32x4 outacc[4][2];
#pragma unroll
  for (int g = 0; g < 4; g++) { outacc[g][0] = zero; outacc[g][1] = zero; }
#pragma unroll
  for (int b = 0; b < 8; b++) {
    int g = b >> 1, kk0 = (b & 1) * 8;
#pragma unroll
    for (int j = 0; j < 8; j++) {
      int kk = kk0 + j;
      bf16x8 a0 = *(const bf16x8*)(&Os[l16 * 520 + kk * 32 + quad * 8]);
      bf16x8 a1 = *(const bf16x8*)(&Os[(16 + l16) * 520 + kk * 32 + quad * 8]);
      outacc[g][0] = mfma16(a0, wb[b & 1][j], outacc[g][0]);
      outacc[g][1] = mfma16(a1, wb[b & 1][j], outacc[g][1]);
    }
    if (b + 2 < 8) load_wout(b + 2, wb[b & 1]);  // distance-2, after last use
  }

  // ---- epilogue: bias + non-temporal store ----
  float* og = out + (size_t)bp * 32 * 256;
#pragma unroll
  for (int g = 0; g < 4; g++) {
    int ntile = wave + g * 4;
    float bias = b_out[ntile * 16 + l16];
#pragma unroll
    for (int mt = 0; mt < 2; mt++) {
      f32x4 a = outacc[g][mt];
#pragma unroll
      for (int rr = 0; rr < 4; rr++)
        __builtin_nontemporal_store(a[rr] + bias,
                                    &og[(mt * 16 + quad * 4 + rr) * 256 + ntile * 16 + l16]);
    }
  }
}

extern "C" void kernel_launch(void* const* d_in, const int* in_sizes, int n_in,
                              void* d_out, int out_size, void* d_ws, size_t ws_size,
                              hipStream_t stream) {
  const float* x    = (const float*)d_in[0];
  const float* Wqkv = (const float*)d_in[1];
  const float* Wout = (const float*)d_in[2];
  const float* bout = (const float*)d_in[3];
  float* out = (float*)d_out;

  __bf16* WqkvP = (__bf16*)d_ws;
  __bf16* WoutP = (__bf16*)((char*)d_ws + (size_t)1536 * 256 * 2);

  prep_weights<<<256, 256, 0, stream>>>(Wqkv, Wout, WqkvP, WoutP);
  attn_fused<<<4096, 256, 0, stream>>>(x, WqkvP, WoutP, bout, out);
}